// Round 5
// baseline (217.352 us; speedup 1.0000x reference)
//
#include <hip/hip_runtime.h>

#define NE 4000
#define NI 1000
#define NT 5000            // total neurons
#define PI_F 3.14159265358979323846f
#define ST 65              // LDS tile row stride (floats): 64 + 1 pad

#define NB_SIM ((NT + 63) / 64)     // 79 sim blocks (1 wave each, 1 neuron/lane)
#define NB_Z   177                  // zero-filler blocks -> 256 total (1 per CU)

// d_out layout (floats): [0,T) Out | [T, T+NT*T) V | next NT*T g | next NT*T spk

// One Euler step in u = tan(theta/2):  u += kk*I - hh + hh*u^2 ;  V = 3.5u - 58.5
#define USTEP(W, VO) {                          \
    float a_ = fmaf(kk, (W), mh);               \
    float s_ = u + a_;                          \
    u = fmaf(hh * u, u, s_);                    \
    umax = fmaxf(umax, u);                      \
    VO = fmaf(3.5f, u, -58.5f);                 \
}

// Cooperative tile load: 64 rows x 16 float4 cols; wave reads 1KiB contiguous
// per unrolled iteration (4 rows x 256B). Rows/cols clamped (duplicates benign).
__device__ __forceinline__ void load_tile_regs(const float* __restrict__ Input,
                                               int i0, int T, int c0, int lane,
                                               float4* tmp)
{
    #pragma unroll
    for (int it = 0; it < 16; ++it) {
        int f = it * 64 + lane;
        int r = f >> 4;
        int q = f & 15;
        int row = i0 + r; row = (row < NT) ? row : (NT - 1);
        int col = c0 + 4 * q; col = (col <= T - 4) ? col : (T - 4);
        tmp[it] = *(const float4*)(Input + (long)row * T + col);
    }
}

__device__ __forceinline__ void write_tile_lds(float* lds, int lane, const float4* tmp)
{
    #pragma unroll
    for (int it = 0; it < 16; ++it) {
        int f = it * 64 + lane;
        int r = f >> 4;
        int q = f & 15;
        *(float4*)(lds + r * ST + 4 * q) = tmp[it];
    }
}

template<bool FIRST, int NQV>
__device__ __forceinline__ void compute_chunk(const float* ain, float* vt, int lane,
                                              float kk, float hh, float mh,
                                              float& u, float& umax)
{
    const float* rp = ain + lane * ST;
    float* wp = vt + lane * ST;
    #pragma unroll
    for (int j = 0; j < NQV; ++j) {
        float4 w = *(const float4*)(rp + 4 * j);      // ds_read_b128
        float4 v;
        if (FIRST && j == 0) { v.x = -58.5f; }        // t=0: no update, V=theta2V(0)
        else                 { USTEP(w.x, v.x); }
        USTEP(w.y, v.y);
        USTEP(w.z, v.z);
        USTEP(w.w, v.w);
        *(float4*)(wp + 4 * j) = v;                    // ds_write_b128
    }
}

template<int NQV>
__device__ __forceinline__ void store_tile(const float* vt, float* __restrict__ V,
                                           int i0, int T, int c0, int lane)
{
    #pragma unroll
    for (int it = 0; it < 16; ++it) {
        int f = it * 64 + lane;
        int r = f >> 4;
        int q = f & 15;
        if (q < NQV) {
            float4 v = *(const float4*)(vt + r * ST + 4 * q);
            int row = i0 + r; row = (row < NT) ? row : (NT - 1);
            *(float4*)(V + (long)row * T + c0 + 4 * q) = v;
        }
    }
}

// Optimistic decoupled integration in half-angle coords. Blocks >= NB_SIM zero
// the g/spk/Out regions concurrently on otherwise-idle CUs.
__global__ __launch_bounds__(64, 1) void sim_nospike(
    const float* __restrict__ Input, const float* __restrict__ dtp,
    float* __restrict__ out, int T, int* __restrict__ flags)
{
    const int lane = threadIdx.x;
    const int b = blockIdx.x;

    if (b >= NB_SIM) {                       // ---- zeroing path ----
        const float4 z4 = make_float4(0.f, 0.f, 0.f, 0.f);
        long zidx = (long)(b - NB_SIM) * 64 + lane;
        long zstride = (long)NB_Z * 64;
        float4* gz = (float4*)(out + T + (long)NT * T);   // g+spk contiguous
        const long n4 = (long)NT * T / 2;
        for (long k = zidx; k < n4; k += zstride) gz[k] = z4;
        if (b == NB_SIM) {
            float4* oz = (float4*)out;
            for (int idx = lane; idx < T / 4; idx += 64) oz[idx] = z4;
        }
        return;
    }

    __shared__ float ain[2][64 * ST];
    __shared__ float vt[64 * ST];

    const int i0 = b * 64;
    int i = i0 + lane; if (i >= NT) i = NT - 1;
    const float dt = dtp[0];
    const float gl = (i < NE) ? 0.08f : 0.1f;
    const float kk = (2.0f / 7.0f) * dt;     // C0*dt
    const float hh = 0.5f * gl * dt;
    const float mh = -hh;
    float* V = out + T;
    float u = 0.f, umax = -1e30f;

    const int NCH = T >> 6;
    const int rem = T & 63;
    const bool partial40 = (rem == 40);      // T=1000 case
    float4 tmp[16];

    if (NCH > 0) {
        load_tile_regs(Input, i0, T, 0, lane, tmp);
        write_tile_lds(&ain[0][0], lane, tmp);
        for (int c = 0; c < NCH; ++c) {
            bool havenext = (c + 1 < NCH) || ((c + 1 == NCH) && partial40);
            if (havenext)                     // prefetch next tile into regs
                load_tile_regs(Input, i0, T, (c + 1) * 64, lane, tmp);
            if (c == 0)
                compute_chunk<true, 16>(&ain[0][0], vt, lane, kk, hh, mh, u, umax);
            else
                compute_chunk<false, 16>(&ain[c & 1][0], vt, lane, kk, hh, mh, u, umax);
            store_tile<16>(vt, V, i0, T, c * 64, lane);
            if (havenext)
                write_tile_lds(&ain[(c + 1) & 1][0], lane, tmp);
        }
        if (partial40) {
            compute_chunk<false, 10>(&ain[NCH & 1][0], vt, lane, kk, hh, mh, u, umax);
            store_tile<10>(vt, V, i0, T, NCH * 64, lane);
        } else {
            const float* ip = Input + (long)i * T;
            float* vrow = V + (long)i * T;
            for (int t = NCH * 64; t < T; ++t) {
                float w = ip[t], v;
                USTEP(w, v);
                vrow[t] = v;
            }
        }
    } else {
        const float* ip = Input + (long)i * T;
        float* vrow = V + (long)i * T;
        for (int t = 0; t < T; ++t) {
            float w = ip[t], v;
            if (t == 0) { v = -58.5f; }
            else        { USTEP(w, v); }
            vrow[t] = v;
        }
    }

    // conservative spike flag: theta >= pi requires crossing u = tan(theta/2) >= 1
    unsigned long long ball = __ballot(umax >= 1.0f);
    if (lane == 0) flags[b] = (ball != 0ULL) ? 1 : 0;
}

// Exact sequential fallback (only executes if a spike was flagged).
__global__ __launch_bounds__(1024) void fallback(
    const float* __restrict__ Input, const float* __restrict__ conn,
    const float* __restrict__ Wout, const float* __restrict__ dtp,
    const int* __restrict__ tauEp, const int* __restrict__ tauIp,
    float* __restrict__ out, int T, const int* __restrict__ flags, int nb)
{
    __shared__ int any;
    const int tid = threadIdx.x;
    if (tid == 0) any = 0;
    __syncthreads();
    if (tid < nb && flags[tid] != 0) any = 1;
    __syncthreads();
    if (any == 0) return;                   // uniform: optimistic path valid

    const float dt = *dtp;
    const float tauE = (float)(*tauEp), tauI = (float)(*tauIp);
    const float C0 = (float)(2.0 / 7.0);
    const float C1 = (float)(117.0 / 7.0);
    const float C2 = (float)(-23.0 / 7.0);
    const int BLK = 1024;
    const int K = 5;                        // 5*1024 >= 5000

    __shared__ int cntE, cntI;
    __shared__ int listE[NE];
    __shared__ int listI[NI];
    __shared__ float red[1024];

    float gA[K], gB[K], gC[K], ph[K];
    for (int k = 0; k < K; ++k) { gA[k] = gB[k] = gC[k] = 0.f; ph[k] = 0.f; }
    if (tid == 0) { cntE = 0; cntI = 0; }

    float* Vout = out + T;
    float* Gout = out + T + (long)NT * T;
    float* Sout = out + T + 2L * (long)NT * T;
    for (int k = 0; k < K; ++k) {
        int i = tid + k * BLK;
        if (i < NT) Vout[(long)i * T] = -58.5f;
    }
    __syncthreads();

    for (int t = 1; t < T; ++t) {
        int nEs = cntE, nIs = cntI;         // spikes from step t-1
        float outpart = 0.f;
        for (int k = 0; k < K; ++k) {
            int i = tid + k * BLK;
            if (i >= NT) break;
            const float* crow = conn + (long)i * NT;
            float mA = 0.f, mB = 0.f;
            for (int j = 0; j < nEs; ++j) mA += crow[listE[j]];
            for (int j = 0; j < nIs; ++j) mB += crow[listI[j]];
            bool isE = i < NE;
            float tau = isE ? tauE : tauI;
            float gpA = isE ? 0.004069f : 0.003276f;
            float gpB = isE ? 0.02672f  : 0.02138f;
            gA[k] = gA[k] + (-gA[k] / tau + gpA * mA) * dt;
            gB[k] = gB[k] + (-gB[k] / tau + gpB * mB) * dt;
            gC[k] = gC[k] + (-gC[k] / tau + gpA * mA + gpB * mB) * dt;
            Gout[(long)i * T + t] = gC[k];
            outpart += gC[k] * Wout[i];
        }
        __syncthreads();                    // all done reading lists
        if (tid == 0) { cntE = 0; cntI = 0; }
        red[tid] = outpart;
        __syncthreads();
        for (int sd = BLK / 2; sd > 0; sd >>= 1) {
            if (tid < sd) red[tid] += red[tid + sd];
            __syncthreads();
        }
        if (tid == 0) out[t] = red[0] / (float)NT;

        for (int k = 0; k < K; ++k) {
            int i = tid + k * BLK;
            if (i >= NT) break;
            bool isE = i < NE;
            float gl = isE ? 0.08f : 0.1f;
            float inp = Input[(long)i * T + t];
            float s, c;
            sincosf(ph[k], &s, &c);
            float ph2 = ph[k] + (-gl * c + C0 * (1.f + c) * inp
                                 + gA[k] * (C1 * (1.f + c) - s)
                                 + gB[k] * (C2 * (1.f + c) - s)) * dt;
            float spkv = 0.f;
            if (ph2 >= PI_F) {
                spkv = 1.f;
                ph2 -= 2.f * PI_F;
                int pos = isE ? atomicAdd(&cntE, 1) : atomicAdd(&cntI, 1);
                if (isE) listE[pos] = i; else listI[pos] = i;
            }
            ph[k] = ph2;
            Sout[(long)i * T + t] = spkv;
            Vout[(long)i * T + t] = fmaf(3.5f, tanf(ph2 * 0.5f), -58.5f);
        }
        __syncthreads();                    // lists complete for next step
    }
}

extern "C" void kernel_launch(void* const* d_in, const int* in_sizes, int n_in,
                              void* d_out, int out_size, void* d_ws, size_t ws_size,
                              hipStream_t stream)
{
    const float* dt    = (const float*)d_in[0];
    const float* Input = (const float*)d_in[1];
    const float* conn  = (const float*)d_in[2];
    const float* Wout  = (const float*)d_in[3];
    const int*   tauE  = (const int*)d_in[6];
    const int*   tauI  = (const int*)d_in[7];
    int T = in_sizes[1] / NT;
    float* out = (float*)d_out;
    int* flags = (int*)d_ws;

    sim_nospike<<<NB_SIM + NB_Z, 64, 0, stream>>>(Input, dt, out, T, flags);
    fallback<<<1, 1024, 0, stream>>>(Input, conn, Wout, dt, tauE, tauI, out, T, flags, NB_SIM);
}